// Round 6
// baseline (168.096 us; speedup 1.0000x reference)
//
#include <hip/hip_runtime.h>

// PeriodicEmbedding: out[b, n*64+o] = relu( sum_i emb[b,n,i] * W[n,i,o] + bias[n,o] )
//   emb[b,n,i] = sin(2*pi*coef[n,i]*x[b,n])     i in [0,32)
//              = cos(2*pi*coef[n,i-32]*x[b,n])  i in [32,64)
// B=8192, N=256, D=64. Output f32 512 MB, written once, never re-read.
//
// History:
//  R0 108.8 us  LDS-staged, scalar stores.
//  R1 164.4 us  REGRESSION: ws-preconverted W (cold fragment loads).
//  R2 108.4 us  = R0: float4 stores + staging amortization worth ~0.
//  R3 111.7 us  XCD token remap ~0.
//  R4 117.8 us  token-blocked 1KB/row runs WORSE (36KB LDS -> half occupancy).
//     => footprint shape exonerated; plateau = mixed-stream ceiling OR L2 write
//        pollution. R5 tests the last lever: NONTEMPORAL stores (nt-flagged
//        dwordx4) so the write stream bypasses L2, leaving it to W/x reads.
//  R5 = R2 base + __builtin_nontemporal_store. Single-variable change.

typedef short bf16x8 __attribute__((ext_vector_type(8)));
typedef float f32x4 __attribute__((ext_vector_type(4)));

#define BM    128   // rows per tile (4 waves x 32 rows)
#define TILES 4     // tiles per block -> 512 rows per block
#define LDW   72    // LDS row stride (bf16): 144 B, keeps ds_read_b128 16B-aligned

__device__ __forceinline__ short f2bf(float f) {
    unsigned u = __float_as_uint(f);
    unsigned r = (u + 0x7FFFu + ((u >> 16) & 1u)) >> 16;   // RNE
    return (short)r;
}

__global__ __launch_bounds__(256) void pe_kernel(
    const float* __restrict__ x,     // [B, N]
    const float* __restrict__ coef,  // [N, 32]
    const float* __restrict__ wgt,   // [N, 64, 64]  (i=k, o)
    const float* __restrict__ bias,  // [N, 64]
    float* __restrict__ out)         // [B, 16384]
{
    const int N = 256;
    const int bid = blockIdx.x;
    const int n      = bid & (N - 1);                 // token fastest -> x-line L2 reuse
    const int b_base = (bid >> 8) * (BM * TILES);

    __shared__ short wtl[64 * LDW];                   // Wt[o][k] bf16
    const int t = threadIdx.x;

    // ---- stage W[n] transposed into LDS as bf16 (once per block) ----
    const float* Wn = wgt + n * 4096;
    #pragma unroll
    for (int it = 0; it < 16; ++it) {
        int idx = it * 256 + t;                       // coalesced f32 read
        int i = idx >> 6, o = idx & 63;               // W[n][i][o]
        wtl[o * LDW + i] = f2bf(Wn[idx]);
    }
    __syncthreads();

    const int w  = t >> 6;
    const int l  = t & 63;
    const int lr = l & 15;
    const int lg = l >> 4;

    // ---- W fragments (A operand: row = o = nf*16+lr, k = ki*32+lg*8+j), once ----
    bf16x8 bfr[4][2];
    #pragma unroll
    for (int nf = 0; nf < 4; ++nf)
        #pragma unroll
        for (int ki = 0; ki < 2; ++ki)
            bfr[nf][ki] = *(const bf16x8*)(&wtl[(nf * 16 + lr) * LDW + ki * 32 + lg * 8]);

    // ---- coef slice for this lane's k slots, once ----
    const float* cp = coef + n * 32 + lg * 8;
    float c[8];
    #pragma unroll
    for (int jj = 0; jj < 8; ++jj) c[jj] = cp[jj];

    // ---- bias (o = nf*16 + lg*4 + q), once ----
    const float* bn = bias + n * 64;
    f32x4 bv[4];
    #pragma unroll
    for (int nf = 0; nf < 4; ++nf)
        bv[nf] = *(const f32x4*)(bn + nf * 16 + lg * 4);

    // ---- per-tile: x load -> sincos -> MFMA -> nt-store ----
    for (int tt = 0; tt < TILES; ++tt) {
        const int b0   = b_base + tt * BM;
        const int row0 = b0 + w * 32 + lr;
        const float x0 = x[row0 * N + n];
        const float x1 = x[(row0 + 16) * N + n];

        // emb fragments (B operand: col = out-block row = lr, k = lg*8+j)
        bf16x8 a_s[2], a_c[2];
        #pragma unroll
        for (int m = 0; m < 2; ++m) {
            float xv = m ? x1 : x0;
            #pragma unroll
            for (int jj = 0; jj < 8; ++jj) {
                float v = c[jj] * xv;
                v = __builtin_amdgcn_fractf(v);            // sin(2*pi*t)=v_sin(fract(t))
                a_s[m][jj] = f2bf(__builtin_amdgcn_sinf(v));
                a_c[m][jj] = f2bf(__builtin_amdgcn_cosf(v));
            }
        }

        // D = W x emb: D row = o (4 consecutive per lane), D col = b-row
        f32x4 acc[2][4];
        #pragma unroll
        for (int m = 0; m < 2; ++m)
            #pragma unroll
            for (int nf = 0; nf < 4; ++nf) {
                f32x4 z = {0.f, 0.f, 0.f, 0.f};
                z = __builtin_amdgcn_mfma_f32_16x16x32_bf16(bfr[nf][0], a_s[m], z, 0, 0, 0);
                z = __builtin_amdgcn_mfma_f32_16x16x32_bf16(bfr[nf][1], a_c[m], z, 0, 0, 0);
                acc[m][nf] = z;
            }

        // epilogue: +bias, relu, NONTEMPORAL float4 stores (bypass L2)
        #pragma unroll
        for (int m = 0; m < 2; ++m) {
            int row = b0 + w * 32 + m * 16 + lr;
            float* op = out + (size_t)row * 16384 + n * 64 + lg * 4;
            #pragma unroll
            for (int nf = 0; nf < 4; ++nf) {
                f32x4 v = acc[m][nf] + bv[nf];
                f32x4 r;
                #pragma unroll
                for (int q = 0; q < 4; ++q) r[q] = fmaxf(v[q], 0.0f);
                __builtin_nontemporal_store(r, (f32x4*)(op + nf * 16));
            }
        }
    }
}

extern "C" void kernel_launch(void* const* d_in, const int* in_sizes, int n_in,
                              void* d_out, int out_size, void* d_ws, size_t ws_size,
                              hipStream_t stream) {
    const float* x    = (const float*)d_in[0];
    const float* coef = (const float*)d_in[1];
    const float* wgt  = (const float*)d_in[2];
    const float* bias = (const float*)d_in[3];
    float* out = (float*)d_out;

    dim3 grid(256 * (8192 / (BM * TILES)));   // 4096 blocks, token fastest
    dim3 block(256);
    hipLaunchKernelGGL(pe_kernel, grid, block, 0, stream,
                       x, coef, wgt, bias, out);
}

// Round 7
// 133.761 us; speedup vs baseline: 1.2567x; 1.2567x over previous
//
#include <hip/hip_runtime.h>

// PeriodicEmbedding: out[b, n*64+o] = relu( sum_i emb[b,n,i] * W[n,i,o] + bias[n,o] )
//   emb[b,n,i] = sin(2*pi*coef[n,i]*x[b,n])     i in [0,32)
//              = cos(2*pi*coef[n,i-32]*x[b,n])  i in [32,64)
// B=8192, N=256, D=64. Output f32 512 MB, write-dominated.
//
// History:
//  R0 108.8  LDS-staged, scalar stores.
//  R1 164.4  REGRESSION: per-lane cold global fragment loads.
//  R2 108.4  best: float4 stores, 4 tiles/block.
//  R3 111.7  XCD token remap ~0.   R4 117.8 token-blocked (occupancy loss).
//  R5 168.1  REGRESSION: nontemporal stores -> L2 write-combining is essential.
//  R6 = R2 + read-side cleanup: prep kernel transposes x into ws (column gather
//      was 32x line-amplified, ~64 MB HBM for 8 MB of data) and pre-converts W
//      to bf16 [n][o][k] (2 MB, L2-resident; halves staging bytes, kills cvts).
//      If flat vs R2 -> mixed-stream roofline confirmed.

typedef short bf16x8 __attribute__((ext_vector_type(8)));
typedef float f32x4 __attribute__((ext_vector_type(4)));

#define BM    128   // rows per tile (4 waves x 32 rows)
#define TILES 4     // tiles per block -> 512 rows per block
#define LDW   72    // LDS row stride (bf16): 144 B, keeps ds_read_b128 16B-aligned

__device__ __forceinline__ short f2bf(float f) {
    unsigned u = __float_as_uint(f);
    unsigned r = (u + 0x7FFFu + ((u >> 16) & 1u)) >> 16;   // RNE
    return (short)r;
}

// ---------------- prep: blocks 0..511 transpose x; 512..767 convert W ----------------
__global__ __launch_bounds__(256) void pe_prep(
    const float* __restrict__ x,     // [8192, 256]
    const float* __restrict__ wgt,   // [256, 64, 64] (k, o)
    float* __restrict__ xt,          // [256, 8192]
    short* __restrict__ wt)          // [256][64][64] bf16, (o, k) transposed
{
    const int bid = blockIdx.x;
    const int t   = threadIdx.x;

    if (bid < 512) {
        // ---- x transpose, 16 rows per block ----
        __shared__ float lx[16][257];
        const int R0 = bid * 16;
        #pragma unroll
        for (int it = 0; it < 16; ++it) {
            int idx = it * 256 + t;
            int r = idx >> 8, c = idx & 255;
            lx[r][c] = x[(size_t)(R0 + r) * 256 + c];   // coalesced
        }
        __syncthreads();
        #pragma unroll
        for (int it = 0; it < 4; ++it) {
            int c  = it * 64 + (t >> 2);
            int r0 = (t & 3) * 4;
            f32x4 v;
            #pragma unroll
            for (int q = 0; q < 4; ++q) v[q] = lx[r0 + q][c];
            *(f32x4*)(xt + (size_t)c * 8192 + R0 + r0) = v;
        }
    } else {
        // ---- W f32 [k][o] -> bf16 Wt [o][k], one token per block ----
        __shared__ float lw[64 * 65];
        const int n = bid - 512;
        const float4* Wn4 = (const float4*)(wgt + n * 4096);
        #pragma unroll
        for (int it = 0; it < 4; ++it) {
            int idx4 = it * 256 + t;
            float4 v = Wn4[idx4];                        // coalesced
            int flat = idx4 * 4;
            int k = flat >> 6, o = flat & 63;
            lw[k * 65 + o + 0] = v.x;
            lw[k * 65 + o + 1] = v.y;
            lw[k * 65 + o + 2] = v.z;
            lw[k * 65 + o + 3] = v.w;
        }
        __syncthreads();
        short* op = wt + n * 4096;
        #pragma unroll
        for (int half = 0; half < 2; ++half) {
            int c  = half * 256 + t;
            int o  = c >> 3, k0 = (c & 7) * 8;
            bf16x8 pk;
            #pragma unroll
            for (int j = 0; j < 8; ++j) pk[j] = f2bf(lw[(k0 + j) * 65 + o]);
            *(bf16x8*)(op + c * 8) = pk;                 // coalesced
        }
    }
}

// ---------------- main: R2 structure, reads from xt / wt ----------------
__global__ __launch_bounds__(256) void pe_kernel(
    const float* __restrict__ xt,    // [256, 8192]
    const float* __restrict__ coef,  // [N, 32]
    const short* __restrict__ wt,    // [256][64][64] bf16 (o,k)
    const float* __restrict__ bias,  // [N, 64]
    float* __restrict__ out)         // [B, 16384]
{
    const int N = 256;
    const int bid = blockIdx.x;
    const int n      = bid & (N - 1);                 // token fastest
    const int b_base = (bid >> 8) * (BM * TILES);

    __shared__ short wtl[64 * LDW];                   // Wt[o][k] bf16
    const int t = threadIdx.x;

    // ---- stage Wt[n] into LDS: 2 x (dwordx4 load + b128 LDS write) ----
    const short* wn = wt + n * 4096;
    #pragma unroll
    for (int it = 0; it < 2; ++it) {
        int idx = it * 256 + t;                       // 8 bf16 per chunk
        int o = idx >> 3, k0 = (idx & 7) * 8;
        *(bf16x8*)(&wtl[o * LDW + k0]) = *(const bf16x8*)(wn + idx * 8);
    }
    __syncthreads();

    const int w  = t >> 6;
    const int l  = t & 63;
    const int lr = l & 15;
    const int lg = l >> 4;

    // ---- W fragments (A operand: row = o = nf*16+lr, k = ki*32+lg*8+j), once ----
    bf16x8 bfr[4][2];
    #pragma unroll
    for (int nf = 0; nf < 4; ++nf)
        #pragma unroll
        for (int ki = 0; ki < 2; ++ki)
            bfr[nf][ki] = *(const bf16x8*)(&wtl[(nf * 16 + lr) * LDW + ki * 32 + lg * 8]);

    // ---- coef slice, once ----
    const float* cp = coef + n * 32 + lg * 8;
    float c[8];
    #pragma unroll
    for (int jj = 0; jj < 8; ++jj) c[jj] = cp[jj];

    // ---- bias (o = nf*16 + lg*4 + q), once ----
    const float* bn = bias + n * 64;
    f32x4 bv[4];
    #pragma unroll
    for (int nf = 0; nf < 4; ++nf)
        bv[nf] = *(const f32x4*)(bn + nf * 16 + lg * 4);

    const float* xn = xt + (size_t)n * 8192;

    // ---- per-tile: x load (coalesced from xt) -> sincos -> MFMA -> store ----
    for (int tt = 0; tt < TILES; ++tt) {
        const int b0   = b_base + tt * BM;
        const int row0 = b0 + w * 32 + lr;
        const float x0 = xn[row0];
        const float x1 = xn[row0 + 16];

        bf16x8 a_s[2], a_c[2];
        #pragma unroll
        for (int m = 0; m < 2; ++m) {
            float xv = m ? x1 : x0;
            #pragma unroll
            for (int jj = 0; jj < 8; ++jj) {
                float v = c[jj] * xv;
                v = __builtin_amdgcn_fractf(v);            // sin(2*pi*t)=v_sin(fract(t))
                a_s[m][jj] = f2bf(__builtin_amdgcn_sinf(v));
                a_c[m][jj] = f2bf(__builtin_amdgcn_cosf(v));
            }
        }

        f32x4 acc[2][4];
        #pragma unroll
        for (int m = 0; m < 2; ++m)
            #pragma unroll
            for (int nf = 0; nf < 4; ++nf) {
                f32x4 z = {0.f, 0.f, 0.f, 0.f};
                z = __builtin_amdgcn_mfma_f32_16x16x32_bf16(bfr[nf][0], a_s[m], z, 0, 0, 0);
                z = __builtin_amdgcn_mfma_f32_16x16x32_bf16(bfr[nf][1], a_c[m], z, 0, 0, 0);
                acc[m][nf] = z;
            }

        #pragma unroll
        for (int m = 0; m < 2; ++m) {
            int row = b0 + w * 32 + m * 16 + lr;
            float* op = out + (size_t)row * 16384 + n * 64 + lg * 4;
            #pragma unroll
            for (int nf = 0; nf < 4; ++nf) {
                f32x4 v = acc[m][nf] + bv[nf];
                f32x4 r;
                #pragma unroll
                for (int q = 0; q < 4; ++q) r[q] = fmaxf(v[q], 0.0f);
                *(f32x4*)(op + nf * 16) = r;
            }
        }
    }
}

// ---------------- fallback (ws too small): R2 verbatim ----------------
__global__ __launch_bounds__(256) void pe_fallback(
    const float* __restrict__ x, const float* __restrict__ coef,
    const float* __restrict__ wgt, const float* __restrict__ bias,
    float* __restrict__ out)
{
    const int N = 256;
    const int bid = blockIdx.x;
    const int n      = bid & (N - 1);
    const int b_base = (bid >> 8) * (BM * TILES);

    __shared__ short wtl[64 * LDW];
    const int t = threadIdx.x;

    const float* Wn = wgt + n * 4096;
    #pragma unroll
    for (int it = 0; it < 16; ++it) {
        int idx = it * 256 + t;
        int i = idx >> 6, o = idx & 63;
        wtl[o * LDW + i] = f2bf(Wn[idx]);
    }
    __syncthreads();

    const int w = t >> 6, l = t & 63, lr = l & 15, lg = l >> 4;

    bf16x8 bfr[4][2];
    #pragma unroll
    for (int nf = 0; nf < 4; ++nf)
        #pragma unroll
        for (int ki = 0; ki < 2; ++ki)
            bfr[nf][ki] = *(const bf16x8*)(&wtl[(nf * 16 + lr) * LDW + ki * 32 + lg * 8]);

    const float* cp = coef + n * 32 + lg * 8;
    float c[8];
    #pragma unroll
    for (int jj = 0; jj < 8; ++jj) c[jj] = cp[jj];

    const float* bn = bias + n * 64;
    f32x4 bv[4];
    #pragma unroll
    for (int nf = 0; nf < 4; ++nf)
        bv[nf] = *(const f32x4*)(bn + nf * 16 + lg * 4);

    for (int tt = 0; tt < TILES; ++tt) {
        const int b0   = b_base + tt * BM;
        const int row0 = b0 + w * 32 + lr;
        const float x0 = x[row0 * N + n];
        const float x1 = x[(row0 + 16) * N + n];

        bf16x8 a_s[2], a_c[2];
        #pragma unroll
        for (int m = 0; m < 2; ++m) {
            float xv = m ? x1 : x0;
            #pragma unroll
            for (int jj = 0; jj < 8; ++jj) {
                float v = c[jj] * xv;
                v = __builtin_amdgcn_fractf(v);
                a_s[m][jj] = f2bf(__builtin_amdgcn_sinf(v));
                a_c[m][jj] = f2bf(__builtin_amdgcn_cosf(v));
            }
        }

        f32x4 acc[2][4];
        #pragma unroll
        for (int m = 0; m < 2; ++m)
            #pragma unroll
            for (int nf = 0; nf < 4; ++nf) {
                f32x4 z = {0.f, 0.f, 0.f, 0.f};
                z = __builtin_amdgcn_mfma_f32_16x16x32_bf16(bfr[nf][0], a_s[m], z, 0, 0, 0);
                z = __builtin_amdgcn_mfma_f32_16x16x32_bf16(bfr[nf][1], a_c[m], z, 0, 0, 0);
                acc[m][nf] = z;
            }

        #pragma unroll
        for (int m = 0; m < 2; ++m) {
            int row = b0 + w * 32 + m * 16 + lr;
            float* op = out + (size_t)row * 16384 + n * 64 + lg * 4;
            #pragma unroll
            for (int nf = 0; nf < 4; ++nf) {
                f32x4 v = acc[m][nf] + bv[nf];
                f32x4 r;
                #pragma unroll
                for (int q = 0; q < 4; ++q) r[q] = fmaxf(v[q], 0.0f);
                *(f32x4*)(op + nf * 16) = r;
            }
        }
    }
}

extern "C" void kernel_launch(void* const* d_in, const int* in_sizes, int n_in,
                              void* d_out, int out_size, void* d_ws, size_t ws_size,
                              hipStream_t stream) {
    const float* x    = (const float*)d_in[0];
    const float* coef = (const float*)d_in[1];
    const float* wgt  = (const float*)d_in[2];
    const float* bias = (const float*)d_in[3];
    float* out = (float*)d_out;

    const size_t xt_bytes = (size_t)256 * 8192 * sizeof(float);   // 8 MB
    const size_t wt_bytes = (size_t)256 * 4096 * sizeof(short);   // 2 MB

    if (ws_size >= xt_bytes + wt_bytes) {
        float* xt = (float*)d_ws;
        short* wtp = (short*)((char*)d_ws + xt_bytes);
        hipLaunchKernelGGL(pe_prep, dim3(768), dim3(256), 0, stream, x, wgt, xt, wtp);
        hipLaunchKernelGGL(pe_kernel, dim3(256 * (8192 / (BM * TILES))), dim3(256), 0, stream,
                           (const float*)xt, coef, (const short*)wtp, bias, out);
    } else {
        hipLaunchKernelGGL(pe_fallback, dim3(256 * (8192 / (BM * TILES))), dim3(256), 0, stream,
                           x, coef, wgt, bias, out);
    }
}

// Round 8
// 108.127 us; speedup vs baseline: 1.5546x; 1.2371x over previous
//
#include <hip/hip_runtime.h>

// PeriodicEmbedding: out[b, n*64+o] = relu( sum_i emb[b,n,i] * W[n,i,o] + bias[n,o] )
//   emb[b,n,i] = sin(2*pi*coef[n,i]*x[b,n])     i in [0,32)
//              = cos(2*pi*coef[n,i-32]*x[b,n])  i in [32,64)
// B=8192, N=256, D=64. Output f32 512 MB, written once -> HBM-write-bound.
//
// History (all single-variable experiments):
//  R0 108.8  LDS-staged, scalar stores.
//  R1 164.4  REGRESSION: per-lane cold global fragment loads.
//  R2 108.4  BEST: float4 stores, 4 tiles/block.      <- this file
//  R3 111.7  XCD token remap ~0.
//  R4 117.8  token-blocked 1KB/row runs (LDS 36KB -> half occupancy).
//  R5 168.1  REGRESSION: nontemporal stores (L2 write-combining essential).
//  R6 133.8  REGRESSION: prep-kernel x-transpose + bf16 W (prep + dependency cost
//            exceeded gather savings; L2 already absorbs the x column gather).
// Conclusion: block writes every byte of its output region -> L2 writebacks are
// full lines regardless of store shape; writeback order is eviction-driven and
// uncontrollable from source. 108 us ~= mixed-stream memory roofline.

typedef short bf16x8 __attribute__((ext_vector_type(8)));
typedef float f32x4 __attribute__((ext_vector_type(4)));

#define BM    128   // rows per tile (4 waves x 32 rows)
#define TILES 4     // tiles per block -> 512 rows per block
#define LDW   72    // LDS row stride (bf16): 144 B, keeps ds_read_b128 16B-aligned

__device__ __forceinline__ short f2bf(float f) {
    unsigned u = __float_as_uint(f);
    unsigned r = (u + 0x7FFFu + ((u >> 16) & 1u)) >> 16;   // RNE
    return (short)r;
}

__global__ __launch_bounds__(256) void pe_kernel(
    const float* __restrict__ x,     // [B, N]
    const float* __restrict__ coef,  // [N, 32]
    const float* __restrict__ wgt,   // [N, 64, 64]  (i=k, o)
    const float* __restrict__ bias,  // [N, 64]
    float* __restrict__ out)         // [B, 16384]
{
    const int N = 256;
    const int bid = blockIdx.x;
    const int n      = bid & (N - 1);                 // token fastest -> x-line L2 reuse
    const int b_base = (bid >> 8) * (BM * TILES);

    __shared__ short wtl[64 * LDW];                   // Wt[o][k] bf16
    const int t = threadIdx.x;

    // ---- stage W[n] transposed into LDS as bf16 (once per block) ----
    const float* Wn = wgt + n * 4096;
    #pragma unroll
    for (int it = 0; it < 16; ++it) {
        int idx = it * 256 + t;                       // coalesced f32 read
        int i = idx >> 6, o = idx & 63;               // W[n][i][o]
        wtl[o * LDW + i] = f2bf(Wn[idx]);
    }
    __syncthreads();

    const int w  = t >> 6;
    const int l  = t & 63;
    const int lr = l & 15;
    const int lg = l >> 4;

    // ---- W fragments (A operand: row = o = nf*16+lr, k = ki*32+lg*8+j), once ----
    bf16x8 bfr[4][2];
    #pragma unroll
    for (int nf = 0; nf < 4; ++nf)
        #pragma unroll
        for (int ki = 0; ki < 2; ++ki)
            bfr[nf][ki] = *(const bf16x8*)(&wtl[(nf * 16 + lr) * LDW + ki * 32 + lg * 8]);

    // ---- coef slice for this lane's k slots, once ----
    const float* cp = coef + n * 32 + lg * 8;
    float c[8];
    #pragma unroll
    for (int jj = 0; jj < 8; ++jj) c[jj] = cp[jj];

    // ---- bias (o = nf*16 + lg*4 + q), once ----
    const float* bn = bias + n * 64;
    f32x4 bv[4];
    #pragma unroll
    for (int nf = 0; nf < 4; ++nf)
        bv[nf] = *(const f32x4*)(bn + nf * 16 + lg * 4);

    // ---- per-tile: x load -> sincos -> MFMA -> store ----
    for (int tt = 0; tt < TILES; ++tt) {
        const int b0   = b_base + tt * BM;
        const int row0 = b0 + w * 32 + lr;
        const float x0 = x[row0 * N + n];
        const float x1 = x[(row0 + 16) * N + n];

        // emb fragments (B operand: col = out-block row = lr, k = lg*8+j)
        bf16x8 a_s[2], a_c[2];
        #pragma unroll
        for (int m = 0; m < 2; ++m) {
            float xv = m ? x1 : x0;
            #pragma unroll
            for (int jj = 0; jj < 8; ++jj) {
                float v = c[jj] * xv;
                v = __builtin_amdgcn_fractf(v);            // sin(2*pi*t)=v_sin(fract(t))
                a_s[m][jj] = f2bf(__builtin_amdgcn_sinf(v));
                a_c[m][jj] = f2bf(__builtin_amdgcn_cosf(v));
            }
        }

        // D = W x emb: D row = o (4 consecutive per lane), D col = b-row
        f32x4 acc[2][4];
        #pragma unroll
        for (int m = 0; m < 2; ++m)
            #pragma unroll
            for (int nf = 0; nf < 4; ++nf) {
                f32x4 z = {0.f, 0.f, 0.f, 0.f};
                z = __builtin_amdgcn_mfma_f32_16x16x32_bf16(bfr[nf][0], a_s[m], z, 0, 0, 0);
                z = __builtin_amdgcn_mfma_f32_16x16x32_bf16(bfr[nf][1], a_c[m], z, 0, 0, 0);
                acc[m][nf] = z;
            }

        // epilogue: +bias, relu, float4 stores (o = nf*16 + lg*4 + q contiguous)
        #pragma unroll
        for (int m = 0; m < 2; ++m) {
            int row = b0 + w * 32 + m * 16 + lr;
            float* op = out + (size_t)row * 16384 + n * 64 + lg * 4;
            #pragma unroll
            for (int nf = 0; nf < 4; ++nf) {
                f32x4 v = acc[m][nf] + bv[nf];
                f32x4 r;
                #pragma unroll
                for (int q = 0; q < 4; ++q) r[q] = fmaxf(v[q], 0.0f);
                *(f32x4*)(op + nf * 16) = r;
            }
        }
    }
}

extern "C" void kernel_launch(void* const* d_in, const int* in_sizes, int n_in,
                              void* d_out, int out_size, void* d_ws, size_t ws_size,
                              hipStream_t stream) {
    const float* x    = (const float*)d_in[0];
    const float* coef = (const float*)d_in[1];
    const float* wgt  = (const float*)d_in[2];
    const float* bias = (const float*)d_in[3];
    float* out = (float*)d_out;

    dim3 grid(256 * (8192 / (BM * TILES)));   // 4096 blocks, token fastest
    dim3 block(256);
    hipLaunchKernelGGL(pe_kernel, grid, block, 0, stream,
                       x, coef, wgt, bias, out);
}